// Round 19
// baseline (250.012 us; speedup 1.0000x reference)
//
#include <hip/hip_runtime.h>
#include <hip/hip_bf16.h>
#include <stdint.h>

using u16 = unsigned short;
typedef __bf16 bf16x8 __attribute__((ext_vector_type(8)));
typedef float f32x4 __attribute__((ext_vector_type(4)));
typedef u16 u16x8 __attribute__((ext_vector_type(8)));

__device__ __forceinline__ float bf2f(u16 u) {
  union { unsigned int i; float f; } v; v.i = ((unsigned int)u) << 16; return v.f;
}
__device__ __forceinline__ u16 f2bf(float f) {
  __bf16 h = (__bf16)f;
  return __builtin_bit_cast(u16, h);
}
__device__ __forceinline__ float fexp2(float x) {
  return __builtin_amdgcn_exp2f(x);   // v_exp_f32: natively 2^x
}

__device__ __forceinline__ void gload_lds16(const void* g, void* l) {
  __builtin_amdgcn_global_load_lds(
      (__attribute__((address_space(1))) const void*)g,
      (__attribute__((address_space(3))) void*)l, 16, 0, 0);
}

// ---------------- elementwise convert f32 -> bf16 (8 elems/thread) ----------
__global__ void cvt_f32_bf16(const float* __restrict__ in, u16* __restrict__ out) {
  int i = (blockIdx.x * 256 + threadIdx.x) * 8;
  float4 a = *(const float4*)(in + i);
  float4 b = *(const float4*)(in + i + 4);
  u16x8 o;
  o[0] = f2bf(a.x); o[1] = f2bf(a.y); o[2] = f2bf(a.z); o[3] = f2bf(a.w);
  o[4] = f2bf(b.x); o[5] = f2bf(b.y); o[6] = f2bf(b.z); o[7] = f2bf(b.w);
  *(u16x8*)(out + i) = o;
}

// ---------------- transpose-convert W[K,N] f32 -> Wt[N,K] bf16 --------------
__global__ void transpose_cvt(const float* __restrict__ W, u16* __restrict__ Wt,
                              int K, int N) {
  __shared__ float t[32][33];
  const int tx = threadIdx.x & 31, ty = threadIdx.x >> 5;  // 32x8
  const int n0 = blockIdx.x * 32, k0 = blockIdx.y * 32;
#pragma unroll
  for (int i = 0; i < 32; i += 8)
    t[ty + i][tx] = W[(size_t)(k0 + ty + i) * N + n0 + tx];
  __syncthreads();
#pragma unroll
  for (int i = 0; i < 32; i += 8)
    Wt[(size_t)(n0 + ty + i) * K + k0 + tx] = f2bf(t[tx][ty + i]);
}

// ------- batched transpose-convert of four 1024x1024 weights (one launch) ----
__global__ void transpose_cvt4(const float* __restrict__ Wa, const float* __restrict__ Wb,
                               const float* __restrict__ Wc, const float* __restrict__ Wd,
                               u16* __restrict__ Da, u16* __restrict__ Db,
                               u16* __restrict__ Dc, u16* __restrict__ Dd) {
  __shared__ float t[32][33];
  const int z = blockIdx.z;
  const float* W = (z == 0) ? Wa : (z == 1) ? Wb : (z == 2) ? Wc : Wd;
  u16* D = (z == 0) ? Da : (z == 1) ? Db : (z == 2) ? Dc : Dd;
  const int tx = threadIdx.x & 31, ty = threadIdx.x >> 5;  // 32x8
  const int n0 = blockIdx.x * 32, k0 = blockIdx.y * 32;
#pragma unroll
  for (int i = 0; i < 32; i += 8)
    t[ty + i][tx] = W[(size_t)(k0 + ty + i) * 1024 + n0 + tx];
  __syncthreads();
#pragma unroll
  for (int i = 0; i < 32; i += 8)
    D[(size_t)(n0 + ty + i) * 1024 + k0 + tx] = f2bf(t[tx][ty + i]);
}

// ---------------- transpose V columns of qkv -> vt[bh*64+d][2048] -----------
__global__ void transpose_v(const u16* __restrict__ qkv, u16* __restrict__ vt) {
  __shared__ u16 tile[32][34];
  const int tx = threadIdx.x & 31, ty = threadIdx.x >> 5;  // 32x8
  const int kv0 = blockIdx.x * 32, d0 = blockIdx.y * 32;
  const int bh = blockIdx.z, b = bh >> 4, h = bh & 15;
#pragma unroll
  for (int i = 0; i < 32; i += 8)
    tile[ty + i][tx] = qkv[(size_t)(b * 2048 + kv0 + ty + i) * 3072 + 2048 + h * 64 + d0 + tx];
  __syncthreads();
#pragma unroll
  for (int i = 0; i < 32; i += 8)
    vt[((size_t)bh * 64 + d0 + ty + i) * 2048 + kv0 + tx] = tile[tx][ty + i];
}

// ---------------- concat 3 biases into [3072] --------------------------------
__global__ void concat_bias(const float* __restrict__ bq, const float* __restrict__ bk,
                            const float* __restrict__ bv, float* __restrict__ o) {
  int i = blockIdx.x * 256 + threadIdx.x;
  o[i] = (i < 1024) ? bq[i] : (i < 2048 ? bk[i - 1024] : bv[i - 2048]);
}

// ============ 256x256-tile 8-wave deep-pipelined GEMM (BK=32, ring-4) ========
// C = A[M,K] @ Bt[N,K]^T + bias.  EPI 0: -> bf16   EPI 1: silu -> bf16
template <int EPI>
__global__ __launch_bounds__(512, 2) void gemm256_kernel(
    const u16* __restrict__ A, const u16* __restrict__ Bt,
    const float* __restrict__ bias, u16* __restrict__ outb,
    int M, int N, int K) {
  __shared__ u16 As[4][8192];   // 4 ring slots of [256 rows][32 k] bf16
  __shared__ u16 Bs[4][8192];
  const int t = threadIdx.x;
  const int w = t >> 6, lane = t & 63, lr = lane & 15, lg = lane >> 4;
  const int wm = w >> 2, wn = w & 3;            // 2 x 4 wave grid
  const int gx = gridDim.x;
  const int nwg = gx * gridDim.y;
  const int p = blockIdx.y * gx + blockIdx.x;
  const int L = (p & 7) * (nwg >> 3) + (p >> 3);  // XCD-contiguous swizzle
  const int m0 = (L / gx) * 256, n0 = (L % gx) * 256;

  f32x4 acc[8][4] = {};
  bf16x8 bfr[4];                // B frags held across the two M-sub phases
  const int NKT = K >> 5;

  auto stageA = [&](int kt) {
#pragma unroll
    for (int l = 0; l < 2; ++l) {
      int slot = l * 512 + t;
      int row = slot >> 2, cs = slot & 3;
      int ss = cs ^ ((row >> 1) & 3);           // pre-swizzled source slot
      gload_lds16(&A[(size_t)(m0 + row) * K + kt * 32 + ss * 8], &As[kt & 3][slot * 8]);
    }
  };
  auto stageB = [&](int kt) {
#pragma unroll
    for (int l = 0; l < 2; ++l) {
      int slot = l * 512 + t;
      int row = slot >> 2, cs = slot & 3;
      int ss = cs ^ ((row >> 1) & 3);
      gload_lds16(&Bt[(size_t)(n0 + row) * K + kt * 32 + ss * 8], &Bs[kt & 3][slot * 8]);
    }
  };

  // prologue: stage subtiles 0,1,2; wait until subtile 0 landed
  stageA(0); stageB(0); stageA(1); stageB(1); stageA(2); stageB(2);
  asm volatile("s_waitcnt vmcnt(8)" ::: "memory");
  __builtin_amdgcn_s_barrier();

// one phase: 4(+4) ds_read_b128 (swizzled) + stage + bar + lgkm0 + 16 MFMA
#define PHASE(Q, STAGE)                                                          \
  {                                                                              \
    const u16* Ab = &As[kt & 3][0];                                              \
    bf16x8 af[4];                                                                \
    _Pragma("unroll") for (int m = 0; m < 4; ++m) {                              \
      int row = wm * 128 + ((Q) * 4 + m) * 16 + lr;                              \
      int sl = lg ^ ((row >> 1) & 3);                                            \
      af[m] = *(const bf16x8*)&Ab[row * 32 + sl * 8];                            \
    }                                                                            \
    if ((Q) == 0) {                                                              \
      const u16* Bb = &Bs[kt & 3][0];                                            \
      _Pragma("unroll") for (int n = 0; n < 4; ++n) {                            \
        int row = wn * 64 + n * 16 + lr;                                         \
        int sl = lg ^ ((row >> 1) & 3);                                          \
        bfr[n] = *(const bf16x8*)&Bb[row * 32 + sl * 8];                         \
      }                                                                          \
    }                                                                            \
    STAGE;                                                                       \
    __builtin_amdgcn_s_barrier();                                                \
    asm volatile("s_waitcnt lgkmcnt(0)" ::: "memory");                           \
    __builtin_amdgcn_sched_barrier(0);                                           \
    __builtin_amdgcn_s_setprio(1);                                               \
    _Pragma("unroll") for (int m = 0; m < 4; ++m)                                \
        _Pragma("unroll") for (int n = 0; n < 4; ++n)                            \
            acc[(Q) * 4 + m][n] = __builtin_amdgcn_mfma_f32_16x16x32_bf16(       \
                af[m], bfr[n], acc[(Q) * 4 + m][n], 0, 0, 0);                    \
    __builtin_amdgcn_s_setprio(0);                                               \
  }

  int kt = 0;
  for (; kt < NKT - 3; ++kt) {
    PHASE(0, stageA(kt + 3));
    __builtin_amdgcn_s_barrier();
    PHASE(1, stageB(kt + 3));
    // counted wait: subtiles kt+2, kt+3 stay in flight; kt+1 landed
    asm volatile("s_waitcnt vmcnt(8)" ::: "memory");
    __builtin_amdgcn_s_barrier();
  }
  // tail: everything staged; drain once, then pure compute
  asm volatile("s_waitcnt vmcnt(0)" ::: "memory");
  __builtin_amdgcn_s_barrier();
  for (; kt < NKT; ++kt) {
    PHASE(0, (void)0);
    __builtin_amdgcn_s_barrier();
    PHASE(1, (void)0);
    __builtin_amdgcn_s_barrier();
  }
#undef PHASE

  // epilogue
#pragma unroll
  for (int mf = 0; mf < 8; ++mf)
#pragma unroll
    for (int nf = 0; nf < 4; ++nf)
#pragma unroll
      for (int i = 0; i < 4; ++i) {
        int gr = m0 + wm * 128 + mf * 16 + lg * 4 + i;
        int gc = n0 + wn * 64 + nf * 16 + lr;
        float v = acc[mf][nf][i] + bias[gc];
        if constexpr (EPI == 1) v = v / (1.f + __expf(-v));  // silu
        outb[(size_t)gr * N + gc] = f2bf(v);
      }
}

// ========= GEMM 128x64 tile, ring-4 BK=32, counted-vmcnt (N=1024 shapes) =====
// gemm256's never-drain schedule at nk64's tile: 48KB LDS (unchanged), &3 ring
// index, stages 3 ahead, vmcnt(6) retires exactly stage kt+1 per iteration.
// EPI 2: +resid -> f32+bf16      EPI 3: +resid -> f32
template <int EPI>
__global__ __launch_bounds__(256) void gemm_nk64_kernel(
    const u16* __restrict__ A, const u16* __restrict__ Bt,
    const float* __restrict__ bias, const float* __restrict__ resid,
    u16* __restrict__ outb, float* __restrict__ outf, int M, int N, int K) {
  __shared__ u16 As[4][128 * 32];   // 32 KB
  __shared__ u16 Bs[4][64 * 32];    // 16 KB
  const int t = threadIdx.x;
  const int w = t >> 6, lane = t & 63, lr = lane & 15, lg = lane >> 4;
  const int wm = w >> 1, wn = w & 1;          // 2(M) x 2(N) waves
  const int gx = gridDim.x;                    // N/64
  const int nwg = gx * gridDim.y;
  const int p = blockIdx.y * gx + blockIdx.x;
  const int L = (p & 7) * (nwg >> 3) + (p >> 3);  // XCD-contiguous swizzle
  const int m0 = (L / gx) * 128, n0 = (L % gx) * 64;

  f32x4 acc[4][2] = {};
  const int NKT = K >> 5;

  // 3 gload_lds16 per thread per stage (A: 2, B: 1)
  auto stage = [&](int kt) {
    const int buf = kt & 3;
#pragma unroll
    for (int l = 0; l < 2; ++l) {
      int slot = l * 256 + t;                   // 512 slots x 8 elems = 128x32
      int row = slot >> 2, cs = slot & 3;
      int ss = cs ^ ((row >> 1) & 3);
      gload_lds16(&A[(size_t)(m0 + row) * K + kt * 32 + ss * 8], &As[buf][slot * 8]);
    }
    {
      int slot = t;                             // 256 slots x 8 elems = 64x32
      int row = slot >> 2, cs = slot & 3;
      int ss = cs ^ ((row >> 1) & 3);
      gload_lds16(&Bt[(size_t)(n0 + row) * K + kt * 32 + ss * 8], &Bs[buf][slot * 8]);
    }
  };

#define NK64_COMP(KT)                                                            \
  {                                                                              \
    const u16* Ab = &As[(KT) & 3][0];                                            \
    const u16* Bb = &Bs[(KT) & 3][0];                                            \
    bf16x8 af[4], bfr[2];                                                        \
    _Pragma("unroll") for (int m = 0; m < 4; ++m) {                              \
      int row = wm * 64 + m * 16 + lr;                                           \
      int sl = lg ^ ((row >> 1) & 3);                                            \
      af[m] = *(const bf16x8*)&Ab[row * 32 + sl * 8];                            \
    }                                                                            \
    _Pragma("unroll") for (int n = 0; n < 2; ++n) {                              \
      int row = wn * 32 + n * 16 + lr;                                           \
      int sl = lg ^ ((row >> 1) & 3);                                            \
      bfr[n] = *(const bf16x8*)&Bb[row * 32 + sl * 8];                           \
    }                                                                            \
    asm volatile("s_waitcnt lgkmcnt(0)" ::: "memory");                           \
    __builtin_amdgcn_sched_barrier(0);                                           \
    __builtin_amdgcn_s_setprio(1);                                               \
    _Pragma("unroll") for (int m = 0; m < 4; ++m)                                \
        _Pragma("unroll") for (int n = 0; n < 2; ++n)                            \
          acc[m][n] = __builtin_amdgcn_mfma_f32_16x16x32_bf16(af[m], bfr[n],     \
                                                              acc[m][n], 0, 0, 0);\
    __builtin_amdgcn_s_setprio(0);                                               \
  }

  // prologue: 3 stages issued (9 ops); wait stage 0 landed (keep 6 in flight)
  stage(0); stage(1); stage(2);
  asm volatile("s_waitcnt vmcnt(6)" ::: "memory");
  __builtin_amdgcn_s_barrier();

  int kt = 0;
  for (; kt < NKT - 3; ++kt) {
    stage(kt + 3);               // overwrites slot (kt-1)&3: reads done last iter
    NK64_COMP(kt);
    // 9 outstanding -> retire stage kt+1 only; kt+2, kt+3 stay in flight
    asm volatile("s_waitcnt vmcnt(6)" ::: "memory");
    __builtin_amdgcn_s_barrier();
  }
  // tail: all staged; drain once, then 3 pure-compute iterations (read-only)
  asm volatile("s_waitcnt vmcnt(0)" ::: "memory");
  __builtin_amdgcn_s_barrier();
  for (; kt < NKT; ++kt) {
    NK64_COMP(kt);
  }
#undef NK64_COMP

  const int r0 = m0 + wm * 64, c0 = n0 + wn * 32;
#pragma unroll
  for (int m = 0; m < 4; ++m)
#pragma unroll
    for (int n = 0; n < 2; ++n)
#pragma unroll
      for (int i = 0; i < 4; ++i) {
        int gr = r0 + m * 16 + lg * 4 + i;
        int gc = c0 + n * 16 + lr;
        float v = acc[m][n][i] + bias[gc];
        if constexpr (EPI == 2 || EPI == 3) v += resid[(size_t)gr * N + gc];
        if constexpr (EPI == 2) {
          outf[(size_t)gr * N + gc] = v;
          outb[(size_t)gr * N + gc] = f2bf(v);
        }
        if constexpr (EPI == 3) outf[(size_t)gr * N + gc] = v;
      }
}

// ---------------- causal flash attention: QBLK=128, 8 waves, no-max exp2 -----
__global__ __launch_bounds__(512) void attn_kernel(const u16* __restrict__ qkv,
                                                   const u16* __restrict__ vtg,
                                                   u16* __restrict__ out) {
  __shared__ u16 smem[24576];      // 48 KB
  const int t = threadIdx.x, w = t >> 6, lane = t & 63, lr = lane & 15, lg = lane >> 4;
  const int p = blockIdx.y * 16 + blockIdx.x;
  const int L = (p & 7) * 64 + (p >> 3);          // XCD-contiguous swizzle
  const int qt = 15 - (L & 15), bh = L >> 4, b = bh >> 4, h = bh & 15;
  const int qbw = qt * 128 + w * 16;              // this wave's first q row
  const int jmax_blk = 2 * qt + 1;
  const int jmax_w = 2 * qt + (w >> 2);           // waves 4-7 need the last tile

  // Q pre-scaled by (1/8)*log2(e): QK^T result is directly the exp2 argument
  const float QS = 0.18033688011f;
  bf16x8 qf[2];
#pragma unroll
  for (int kc = 0; kc < 2; ++kc) {
    const u16x8 v = *(const u16x8*)&qkv[(size_t)(b * 2048 + qbw + lr) * 3072 +
                                        h * 64 + kc * 32 + lg * 8];
    bf16x8 q;
#pragma unroll
    for (int jj = 0; jj < 8; ++jj) q[jj] = (__bf16)(bf2f(v[jj]) * QS);
    qf[kc] = q;
  }

  f32x4 yacc[4] = {};
  float S = 0.f;   // per-lane partial denominator

  auto stage = [&](int j, int buf) {
    u16* Kb = smem + buf * 4096;
    u16* Vb = smem + 8192 + buf * 4096;
    int ofs = t * 8;                              // 512 threads x 8 elems = tile
    int row = ofs >> 6, slot = (ofs >> 3) & 7, ss = slot ^ (row & 7);
    gload_lds16(&qkv[(size_t)(b * 2048 + j * 64 + row) * 3072 + 1024 + h * 64 + ss * 8],
                &Kb[ofs]);
    gload_lds16(&vtg[((size_t)bh * 64 + row) * 2048 + j * 64 + ss * 8],
                &Vb[ofs]);
  };

  stage(0, 0);
  __syncthreads();

  for (int j = 0; j <= jmax_blk; ++j) {
    const int cur = j & 1;
    if (j < jmax_blk) stage(j + 1, cur ^ 1);

    if (j <= jmax_w) {
      const char* Kc = (const char*)(smem + cur * 4096);
      const char* Vc = (const char*)(smem + 8192 + cur * 4096);
      char* Pw = (char*)(smem + 16384 + w * 1024);

      // ---- S^T = K @ Q^T : lane holds S[q=lr][k=n*16+lg*4+i] ----
      bf16x8 kf[2][4];
#pragma unroll
      for (int kc = 0; kc < 2; ++kc)
#pragma unroll
        for (int n = 0; n < 4; ++n) {
          int row = n * 16 + lr;
          kf[kc][n] = *(const bf16x8*)(Kc + row * 128 +
                                       ((kc * 64 + lg * 16) ^ ((row & 7) << 4)));
        }
      f32x4 s[4] = {};
#pragma unroll
      for (int n = 0; n < 4; ++n)
#pragma unroll
        for (int kc = 0; kc < 2; ++kc)
          s[n] = __builtin_amdgcn_mfma_f32_16x16x32_bf16(kf[kc][n], qf[kc],
                                                         s[n], 0, 0, 0);
      // causal mask (tiles overlapping the diagonal for this wave)
      if (j * 64 + 63 > qbw) {
#pragma unroll
        for (int n = 0; n < 4; ++n)
#pragma unroll
          for (int i = 0; i < 4; ++i) {
            int kabs = j * 64 + n * 16 + lg * 4 + i;
            int qabs = qbw + lr;
            if (kabs > qabs) s[n][i] = -1e30f;   // exp2 -> 0
          }
      }
      // ---- unnormalized softmax: p = 2^s, per-lane partial sums ----
      {
        float rs = 0.f;
#pragma unroll
        for (int n = 0; n < 4; ++n)
#pragma unroll
          for (int i = 0; i < 4; ++i) {
            float pv = fexp2(s[n][i]);
            s[n][i] = pv;
            rs += pv;
          }
        S += rs;
        const int qrow = lr, sw = (qrow & 7) << 4;
#pragma unroll
        for (int n = 0; n < 4; ++n) {
          ushort4 ph;
          ph.x = f2bf(s[n][0]); ph.y = f2bf(s[n][1]);
          ph.z = f2bf(s[n][2]); ph.w = f2bf(s[n][3]);
          *(ushort4*)(Pw + qrow * 128 + ((n * 32 + lg * 8) ^ sw)) = ph;
        }
      }
      // ---- y += P @ V ----
#pragma unroll
      for (int kc = 0; kc < 2; ++kc) {
        bf16x8 pa, vtf[4];
        {
          int qrow = lr;
          pa = *(const bf16x8*)(Pw + qrow * 128 +
                                ((kc * 64 + lg * 16) ^ ((qrow & 7) << 4)));
        }
#pragma unroll
        for (int n = 0; n < 4; ++n) {
          int row = n * 16 + lr;
          vtf[n] = *(const bf16x8*)(Vc + row * 128 +
                                    ((kc * 64 + lg * 16) ^ ((row & 7) << 4)));
        }
#pragma unroll
        for (int n = 0; n < 4; ++n)
          yacc[n] = __builtin_amdgcn_mfma_f32_16x16x32_bf16(pa, vtf[n],
                                                            yacc[n], 0, 0, 0);
      }
    }
    __syncthreads();
  }

  // epilogue: reduce per-lane partial S across lane^16 / lane^32, normalize
  {
    float Sv = S;
    Sv += __shfl_xor(Sv, 16, 64);
    Sv += __shfl_xor(Sv, 32, 64);
    float inv = 1.f / Sv;
#pragma unroll
    for (int i = 0; i < 4; ++i) {
      float ivq = __shfl(inv, lg * 4 + i, 64);
#pragma unroll
      for (int n = 0; n < 4; ++n) {
        int row = b * 2048 + qbw + lg * 4 + i;
        int col = h * 64 + n * 16 + lr;
        out[(size_t)row * 1024 + col] = f2bf(yacc[n][i] * ivq);
      }
    }
  }
}

// ---------------- host launcher ---------------------------------------------
extern "C" void kernel_launch(void* const* d_in, const int* in_sizes, int n_in,
                              void* d_out, int out_size, void* d_ws, size_t ws_size,
                              hipStream_t stream) {
  const float* x  = (const float*)d_in[0];
  const float* Wq = (const float*)d_in[1];
  const float* bq = (const float*)d_in[2];
  const float* Wk = (const float*)d_in[3];
  const float* bk = (const float*)d_in[4];
  const float* Wv = (const float*)d_in[5];
  const float* bv = (const float*)d_in[6];
  const float* Wo = (const float*)d_in[7];
  const float* bo = (const float*)d_in[8];
  const float* W1 = (const float*)d_in[9];
  const float* b1 = (const float*)d_in[10];
  const float* W2 = (const float*)d_in[11];
  const float* b2 = (const float*)d_in[12];
  float* out = (float*)d_out;

  char* ws = (char*)d_ws;
  const size_t MB = 1u << 20;
  u16*   xb    = (u16*)(ws + 0);         // 8 MB  [4096,1024]  (reused as vtg later)
  u16*   wtqkv = (u16*)(ws + 8 * MB);    // 6 MB  [3072,1024]
  u16*   wto   = (u16*)(ws + 14 * MB);   // 2 MB  [1024,1024]
  u16*   wt1   = (u16*)(ws + 16 * MB);   // 8 MB  [4096,1024]
  u16*   wt2   = (u16*)(ws + 24 * MB);   // 8 MB  [1024,4096]
  float* bqkv  = (float*)(ws + 32 * MB); // 12 KB [3072]
  u16*   qkv   = (u16*)(ws + 33 * MB);   // 24 MB [4096,3072]
  u16*   attn  = (u16*)(ws + 57 * MB);   // 8 MB  [4096,1024]
  float* x2f   = (float*)(ws + 65 * MB); // 16 MB [4096,1024]
  u16*   x2b   = (u16*)(ws + 81 * MB);   // 8 MB  [4096,1024]
  u16*   hbuf  = (u16*)(ws + 89 * MB);   // 32 MB [4096,4096]
  u16*   vtg   = xb;                     // reuse: xb dead after QKV GEMM

  cvt_f32_bf16<<<2048, 256, 0, stream>>>(x, xb);
  // four 1024x1024 weight transposes in one launch
  transpose_cvt4<<<dim3(32, 32, 4), 256, 0, stream>>>(
      Wq, Wk, Wv, Wo, wtqkv, wtqkv + 1024 * 1024, wtqkv + 2 * 1024 * 1024, wto);
  transpose_cvt<<<dim3(128, 32), 256, 0, stream>>>(W1, wt1, 1024, 4096);
  transpose_cvt<<<dim3(32, 128), 256, 0, stream>>>(W2, wt2, 4096, 1024);
  concat_bias<<<12, 256, 0, stream>>>(bq, bk, bv, bqkv);

  // QKV projection (fused, N=3072) — 256^2 deep-pipelined kernel (swizzled)
  gemm256_kernel<0><<<dim3(12, 16), 512, 0, stream>>>(
      xb, wtqkv, bqkv, qkv, 4096, 3072, 1024);
  // V^T for attention PV
  transpose_v<<<dim3(64, 2, 32), 256, 0, stream>>>(qkv, vtg);
  // causal attention — QBLK=128, 8 waves, 512 blocks, 48KB LDS
  attn_kernel<<<dim3(16, 32), 512, 0, stream>>>(qkv, vtg, attn);
  // O projection + residual (f32 and bf16 copies) — ring-4 counted-vmcnt
  gemm_nk64_kernel<2><<<dim3(16, 32), 256, 0, stream>>>(
      attn, wto, bo, x, x2b, x2f, 4096, 1024, 1024);
  // MLP up + SiLU — 256^2 deep-pipelined kernel (swizzled)
  gemm256_kernel<1><<<dim3(16, 16), 512, 0, stream>>>(
      x2b, wt1, b1, hbuf, 4096, 4096, 1024);
  // MLP down + residual -> final f32 output — ring-4 counted-vmcnt
  gemm_nk64_kernel<3><<<dim3(16, 32), 256, 0, stream>>>(
      hbuf, wt2, b2, x2f, nullptr, out, 4096, 1024, 4096);
}

// Round 20
// 220.970 us; speedup vs baseline: 1.1314x; 1.1314x over previous
//
#include <hip/hip_runtime.h>
#include <hip/hip_bf16.h>
#include <stdint.h>

using u16 = unsigned short;
typedef __bf16 bf16x8 __attribute__((ext_vector_type(8)));
typedef float f32x4 __attribute__((ext_vector_type(4)));
typedef u16 u16x8 __attribute__((ext_vector_type(8)));

__device__ __forceinline__ float bf2f(u16 u) {
  union { unsigned int i; float f; } v; v.i = ((unsigned int)u) << 16; return v.f;
}
__device__ __forceinline__ u16 f2bf(float f) {
  __bf16 h = (__bf16)f;
  return __builtin_bit_cast(u16, h);
}
__device__ __forceinline__ float fexp2(float x) {
  return __builtin_amdgcn_exp2f(x);   // v_exp_f32: natively 2^x
}

__device__ __forceinline__ void gload_lds16(const void* g, void* l) {
  __builtin_amdgcn_global_load_lds(
      (__attribute__((address_space(1))) const void*)g,
      (__attribute__((address_space(3))) void*)l, 16, 0, 0);
}

// ---------------- elementwise convert f32 -> bf16 (8 elems/thread) ----------
__global__ void cvt_f32_bf16(const float* __restrict__ in, u16* __restrict__ out) {
  int i = (blockIdx.x * 256 + threadIdx.x) * 8;
  float4 a = *(const float4*)(in + i);
  float4 b = *(const float4*)(in + i + 4);
  u16x8 o;
  o[0] = f2bf(a.x); o[1] = f2bf(a.y); o[2] = f2bf(a.z); o[3] = f2bf(a.w);
  o[4] = f2bf(b.x); o[5] = f2bf(b.y); o[6] = f2bf(b.z); o[7] = f2bf(b.w);
  *(u16x8*)(out + i) = o;
}

// ------- batched transpose-convert of four 1024x1024 weights (one launch) ----
__global__ void transpose_cvt4(const float* __restrict__ Wa, const float* __restrict__ Wb,
                               const float* __restrict__ Wc, const float* __restrict__ Wd,
                               u16* __restrict__ Da, u16* __restrict__ Db,
                               u16* __restrict__ Dc, u16* __restrict__ Dd) {
  __shared__ float t[32][33];
  const int z = blockIdx.z;
  const float* W = (z == 0) ? Wa : (z == 1) ? Wb : (z == 2) ? Wc : Wd;
  u16* D = (z == 0) ? Da : (z == 1) ? Db : (z == 2) ? Dc : Dd;
  const int tx = threadIdx.x & 31, ty = threadIdx.x >> 5;  // 32x8
  const int n0 = blockIdx.x * 32, k0 = blockIdx.y * 32;
#pragma unroll
  for (int i = 0; i < 32; i += 8)
    t[ty + i][tx] = W[(size_t)(k0 + ty + i) * 1024 + n0 + tx];
  __syncthreads();
#pragma unroll
  for (int i = 0; i < 32; i += 8)
    D[(size_t)(n0 + ty + i) * 1024 + k0 + tx] = f2bf(t[tx][ty + i]);
}

// ------- combined transpose-convert of W1 [1024,4096] and W2 [4096,1024] -----
// z=0: W1 (K=1024,N=4096): n0=bx*32, k0=by*32.  z=1: W2 (K=4096,N=1024):
// n0=by*32, k0=bx*32.  Both grids are 128x32 blocks.
__global__ void transpose_cvt_mlp(const float* __restrict__ W1, u16* __restrict__ D1,
                                  const float* __restrict__ W2, u16* __restrict__ D2) {
  __shared__ float t[32][33];
  const int z = blockIdx.z;
  const float* W = z ? W2 : W1;
  u16* D = z ? D2 : D1;
  const int K = z ? 4096 : 1024, N = z ? 1024 : 4096;
  const int tx = threadIdx.x & 31, ty = threadIdx.x >> 5;  // 32x8
  const int n0 = (z ? blockIdx.y : blockIdx.x) * 32;
  const int k0 = (z ? blockIdx.x : blockIdx.y) * 32;
#pragma unroll
  for (int i = 0; i < 32; i += 8)
    t[ty + i][tx] = W[(size_t)(k0 + ty + i) * N + n0 + tx];
  __syncthreads();
#pragma unroll
  for (int i = 0; i < 32; i += 8)
    D[(size_t)(n0 + ty + i) * K + k0 + tx] = f2bf(t[tx][ty + i]);
}

// ---------------- transpose V columns of qkv -> vt[bh*64+d][2048] -----------
__global__ void transpose_v(const u16* __restrict__ qkv, u16* __restrict__ vt) {
  __shared__ u16 tile[32][34];
  const int tx = threadIdx.x & 31, ty = threadIdx.x >> 5;  // 32x8
  const int kv0 = blockIdx.x * 32, d0 = blockIdx.y * 32;
  const int bh = blockIdx.z, b = bh >> 4, h = bh & 15;
#pragma unroll
  for (int i = 0; i < 32; i += 8)
    tile[ty + i][tx] = qkv[(size_t)(b * 2048 + kv0 + ty + i) * 3072 + 2048 + h * 64 + d0 + tx];
  __syncthreads();
#pragma unroll
  for (int i = 0; i < 32; i += 8)
    vt[((size_t)bh * 64 + d0 + ty + i) * 2048 + kv0 + tx] = tile[tx][ty + i];
}

// ---------------- concat 3 biases into [3072] --------------------------------
__global__ void concat_bias(const float* __restrict__ bq, const float* __restrict__ bk,
                            const float* __restrict__ bv, float* __restrict__ o) {
  int i = blockIdx.x * 256 + threadIdx.x;
  o[i] = (i < 1024) ? bq[i] : (i < 2048 ? bk[i - 1024] : bv[i - 2048]);
}

// ============ 256x256-tile 8-wave deep-pipelined GEMM (BK=32, ring-4) ========
// LDS 16B-slots XOR-swizzled (slot^((row>>1)&3), both-sides rule).
// C = A[M,K] @ Bt[N,K]^T + bias.  EPI 0: -> bf16   EPI 1: silu -> bf16
template <int EPI>
__global__ __launch_bounds__(512, 2) void gemm256_kernel(
    const u16* __restrict__ A, const u16* __restrict__ Bt,
    const float* __restrict__ bias, u16* __restrict__ outb,
    int M, int N, int K) {
  __shared__ u16 As[4][8192];   // 4 ring slots of [256 rows][32 k] bf16
  __shared__ u16 Bs[4][8192];
  const int t = threadIdx.x;
  const int w = t >> 6, lane = t & 63, lr = lane & 15, lg = lane >> 4;
  const int wm = w >> 2, wn = w & 3;            // 2 x 4 wave grid
  const int gx = gridDim.x;
  const int nwg = gx * gridDim.y;
  const int p = blockIdx.y * gx + blockIdx.x;
  const int L = (p & 7) * (nwg >> 3) + (p >> 3);  // XCD-contiguous swizzle
  const int m0 = (L / gx) * 256, n0 = (L % gx) * 256;

  f32x4 acc[8][4] = {};
  bf16x8 bfr[4];                // B frags held across the two M-sub phases
  const int NKT = K >> 5;

  auto stageA = [&](int kt) {
#pragma unroll
    for (int l = 0; l < 2; ++l) {
      int slot = l * 512 + t;
      int row = slot >> 2, cs = slot & 3;
      int ss = cs ^ ((row >> 1) & 3);           // pre-swizzled source slot
      gload_lds16(&A[(size_t)(m0 + row) * K + kt * 32 + ss * 8], &As[kt & 3][slot * 8]);
    }
  };
  auto stageB = [&](int kt) {
#pragma unroll
    for (int l = 0; l < 2; ++l) {
      int slot = l * 512 + t;
      int row = slot >> 2, cs = slot & 3;
      int ss = cs ^ ((row >> 1) & 3);
      gload_lds16(&Bt[(size_t)(n0 + row) * K + kt * 32 + ss * 8], &Bs[kt & 3][slot * 8]);
    }
  };

  // prologue: stage subtiles 0,1,2; wait until subtile 0 landed
  stageA(0); stageB(0); stageA(1); stageB(1); stageA(2); stageB(2);
  asm volatile("s_waitcnt vmcnt(8)" ::: "memory");
  __builtin_amdgcn_s_barrier();

// one phase: 4(+4) ds_read_b128 (swizzled) + stage + bar + lgkm0 + 16 MFMA
#define PHASE(Q, STAGE)                                                          \
  {                                                                              \
    const u16* Ab = &As[kt & 3][0];                                              \
    bf16x8 af[4];                                                                \
    _Pragma("unroll") for (int m = 0; m < 4; ++m) {                              \
      int row = wm * 128 + ((Q) * 4 + m) * 16 + lr;                              \
      int sl = lg ^ ((row >> 1) & 3);                                            \
      af[m] = *(const bf16x8*)&Ab[row * 32 + sl * 8];                            \
    }                                                                            \
    if ((Q) == 0) {                                                              \
      const u16* Bb = &Bs[kt & 3][0];                                            \
      _Pragma("unroll") for (int n = 0; n < 4; ++n) {                            \
        int row = wn * 64 + n * 16 + lr;                                         \
        int sl = lg ^ ((row >> 1) & 3);                                          \
        bfr[n] = *(const bf16x8*)&Bb[row * 32 + sl * 8];                         \
      }                                                                          \
    }                                                                            \
    STAGE;                                                                       \
    __builtin_amdgcn_s_barrier();                                                \
    asm volatile("s_waitcnt lgkmcnt(0)" ::: "memory");                           \
    __builtin_amdgcn_sched_barrier(0);                                           \
    __builtin_amdgcn_s_setprio(1);                                               \
    _Pragma("unroll") for (int m = 0; m < 4; ++m)                                \
        _Pragma("unroll") for (int n = 0; n < 4; ++n)                            \
            acc[(Q) * 4 + m][n] = __builtin_amdgcn_mfma_f32_16x16x32_bf16(       \
                af[m], bfr[n], acc[(Q) * 4 + m][n], 0, 0, 0);                    \
    __builtin_amdgcn_s_setprio(0);                                               \
  }

  int kt = 0;
  for (; kt < NKT - 3; ++kt) {
    PHASE(0, stageA(kt + 3));
    __builtin_amdgcn_s_barrier();
    PHASE(1, stageB(kt + 3));
    // counted wait: subtiles kt+2, kt+3 stay in flight; kt+1 landed
    asm volatile("s_waitcnt vmcnt(8)" ::: "memory");
    __builtin_amdgcn_s_barrier();
  }
  // tail: everything staged; drain once, then pure compute
  asm volatile("s_waitcnt vmcnt(0)" ::: "memory");
  __builtin_amdgcn_s_barrier();
  for (; kt < NKT; ++kt) {
    PHASE(0, (void)0);
    __builtin_amdgcn_s_barrier();
    PHASE(1, (void)0);
    __builtin_amdgcn_s_barrier();
  }
#undef PHASE

  // epilogue
#pragma unroll
  for (int mf = 0; mf < 8; ++mf)
#pragma unroll
    for (int nf = 0; nf < 4; ++nf)
#pragma unroll
      for (int i = 0; i < 4; ++i) {
        int gr = m0 + wm * 128 + mf * 16 + lg * 4 + i;
        int gc = n0 + wn * 64 + nf * 16 + lr;
        float v = acc[mf][nf][i] + bias[gc];
        if constexpr (EPI == 1) v = v / (1.f + __expf(-v));  // silu
        outb[(size_t)gr * N + gc] = f2bf(v);
      }
}

// ---------------- GEMM 128x64 tile, double-buffered (N=1024 shapes) ----------
// FINAL: 5 structural variants (R9 ring-3, R11 2-pass, R13 atomic 128^2,
// R17 atomic 256^2, R19 ring-4 BK32) all regressed vs this form.
// EPI 2: +resid -> f32+bf16      EPI 3: +resid -> f32
template <int EPI>
__global__ __launch_bounds__(256) void gemm_nk64_kernel(
    const u16* __restrict__ A, const u16* __restrict__ Bt,
    const float* __restrict__ bias, const float* __restrict__ resid,
    u16* __restrict__ outb, float* __restrict__ outf, int M, int N, int K) {
  __shared__ u16 As[2][128 * 64];
  __shared__ u16 Bs[2][64 * 64];
  const int t = threadIdx.x;
  const int w = t >> 6, lane = t & 63, lr = lane & 15, lg = lane >> 4;
  const int wm = w >> 1, wn = w & 1;          // 2(M) x 2(N) waves
  const int gx = gridDim.x;                    // N/64
  const int nwg = gx * gridDim.y;
  const int p = blockIdx.y * gx + blockIdx.x;
  const int L = (p & 7) * (nwg >> 3) + (p >> 3);  // XCD-contiguous swizzle
  const int m0 = (L / gx) * 128, n0 = (L % gx) * 64;

  f32x4 acc[4][2] = {};
  const int nt = K >> 6;

  auto stage = [&](int kt, int buf) {
#pragma unroll
    for (int it = 0; it < 4; ++it) {
      int ofs = (it * 256 + t) * 8;
      int row = ofs >> 6, slot = (ofs >> 3) & 7, ss = slot ^ (row & 7);
      gload_lds16(&A[(size_t)(m0 + row) * K + kt * 64 + ss * 8], &As[buf][ofs]);
    }
#pragma unroll
    for (int it = 0; it < 2; ++it) {
      int ofs = (it * 256 + t) * 8;
      int row = ofs >> 6, slot = (ofs >> 3) & 7, ss = slot ^ (row & 7);
      gload_lds16(&Bt[(size_t)(n0 + row) * K + kt * 64 + ss * 8], &Bs[buf][ofs]);
    }
  };

  stage(0, 0);
  __syncthreads();

  for (int kt = 0; kt < nt; ++kt) {
    const int cur = kt & 1;
    if (kt + 1 < nt) stage(kt + 1, cur ^ 1);   // issue next-tile loads early
#pragma unroll
    for (int kk = 0; kk < 64; kk += 32) {
      const int kcol = kk + lg * 8;
      bf16x8 af[4], bfr[2];
#pragma unroll
      for (int m = 0; m < 4; ++m) {
        int row = wm * 64 + m * 16 + lr;
        int ss = (kcol >> 3) ^ (row & 7);
        af[m] = *(const bf16x8*)&As[cur][row * 64 + ss * 8];
      }
#pragma unroll
      for (int n = 0; n < 2; ++n) {
        int row = wn * 32 + n * 16 + lr;
        int ss = (kcol >> 3) ^ (row & 7);
        bfr[n] = *(const bf16x8*)&Bs[cur][row * 64 + ss * 8];
      }
#pragma unroll
      for (int m = 0; m < 4; ++m)
#pragma unroll
        for (int n = 0; n < 2; ++n)
          acc[m][n] = __builtin_amdgcn_mfma_f32_16x16x32_bf16(af[m], bfr[n],
                                                              acc[m][n], 0, 0, 0);
    }
    __syncthreads();   // drains vmcnt (next tile landed) + lgkm, barrier
  }

  const int r0 = m0 + wm * 64, c0 = n0 + wn * 32;
#pragma unroll
  for (int m = 0; m < 4; ++m)
#pragma unroll
    for (int n = 0; n < 2; ++n)
#pragma unroll
      for (int i = 0; i < 4; ++i) {
        int gr = r0 + m * 16 + lg * 4 + i;
        int gc = c0 + n * 16 + lr;
        float v = acc[m][n][i] + bias[gc];
        if constexpr (EPI == 2 || EPI == 3) v += resid[(size_t)gr * N + gc];
        if constexpr (EPI == 2) {
          outf[(size_t)gr * N + gc] = v;
          outb[(size_t)gr * N + gc] = f2bf(v);
        }
        if constexpr (EPI == 3) outf[(size_t)gr * N + gc] = v;
      }
}

// ---------------- causal flash attention: QBLK=128, 8 waves, no-max exp2 -----
__global__ __launch_bounds__(512) void attn_kernel(const u16* __restrict__ qkv,
                                                   const u16* __restrict__ vtg,
                                                   u16* __restrict__ out) {
  __shared__ u16 smem[24576];      // 48 KB
  const int t = threadIdx.x, w = t >> 6, lane = t & 63, lr = lane & 15, lg = lane >> 4;
  const int p = blockIdx.y * 16 + blockIdx.x;
  const int L = (p & 7) * 64 + (p >> 3);          // XCD-contiguous swizzle
  const int qt = 15 - (L & 15), bh = L >> 4, b = bh >> 4, h = bh & 15;
  const int qbw = qt * 128 + w * 16;              // this wave's first q row
  const int jmax_blk = 2 * qt + 1;
  const int jmax_w = 2 * qt + (w >> 2);           // waves 4-7 need the last tile

  // Q pre-scaled by (1/8)*log2(e): QK^T result is directly the exp2 argument
  const float QS = 0.18033688011f;
  bf16x8 qf[2];
#pragma unroll
  for (int kc = 0; kc < 2; ++kc) {
    const u16x8 v = *(const u16x8*)&qkv[(size_t)(b * 2048 + qbw + lr) * 3072 +
                                        h * 64 + kc * 32 + lg * 8];
    bf16x8 q;
#pragma unroll
    for (int jj = 0; jj < 8; ++jj) q[jj] = (__bf16)(bf2f(v[jj]) * QS);
    qf[kc] = q;
  }

  f32x4 yacc[4] = {};
  float S = 0.f;   // per-lane partial denominator

  auto stage = [&](int j, int buf) {
    u16* Kb = smem + buf * 4096;
    u16* Vb = smem + 8192 + buf * 4096;
    int ofs = t * 8;                              // 512 threads x 8 elems = tile
    int row = ofs >> 6, slot = (ofs >> 3) & 7, ss = slot ^ (row & 7);
    gload_lds16(&qkv[(size_t)(b * 2048 + j * 64 + row) * 3072 + 1024 + h * 64 + ss * 8],
                &Kb[ofs]);
    gload_lds16(&vtg[((size_t)bh * 64 + row) * 2048 + j * 64 + ss * 8],
                &Vb[ofs]);
  };

  stage(0, 0);
  __syncthreads();

  for (int j = 0; j <= jmax_blk; ++j) {
    const int cur = j & 1;
    if (j < jmax_blk) stage(j + 1, cur ^ 1);

    if (j <= jmax_w) {
      const char* Kc = (const char*)(smem + cur * 4096);
      const char* Vc = (const char*)(smem + 8192 + cur * 4096);
      char* Pw = (char*)(smem + 16384 + w * 1024);

      // ---- S^T = K @ Q^T : lane holds S[q=lr][k=n*16+lg*4+i] ----
      bf16x8 kf[2][4];
#pragma unroll
      for (int kc = 0; kc < 2; ++kc)
#pragma unroll
        for (int n = 0; n < 4; ++n) {
          int row = n * 16 + lr;
          kf[kc][n] = *(const bf16x8*)(Kc + row * 128 +
                                       ((kc * 64 + lg * 16) ^ ((row & 7) << 4)));
        }
      f32x4 s[4] = {};
#pragma unroll
      for (int n = 0; n < 4; ++n)
#pragma unroll
        for (int kc = 0; kc < 2; ++kc)
          s[n] = __builtin_amdgcn_mfma_f32_16x16x32_bf16(kf[kc][n], qf[kc],
                                                         s[n], 0, 0, 0);
      // causal mask (tiles overlapping the diagonal for this wave)
      if (j * 64 + 63 > qbw) {
#pragma unroll
        for (int n = 0; n < 4; ++n)
#pragma unroll
          for (int i = 0; i < 4; ++i) {
            int kabs = j * 64 + n * 16 + lg * 4 + i;
            int qabs = qbw + lr;
            if (kabs > qabs) s[n][i] = -1e30f;   // exp2 -> 0
          }
      }
      // ---- unnormalized softmax: p = 2^s, per-lane partial sums ----
      {
        float rs = 0.f;
#pragma unroll
        for (int n = 0; n < 4; ++n)
#pragma unroll
          for (int i = 0; i < 4; ++i) {
            float pv = fexp2(s[n][i]);
            s[n][i] = pv;
            rs += pv;
          }
        S += rs;
        const int qrow = lr, sw = (qrow & 7) << 4;
#pragma unroll
        for (int n = 0; n < 4; ++n) {
          ushort4 ph;
          ph.x = f2bf(s[n][0]); ph.y = f2bf(s[n][1]);
          ph.z = f2bf(s[n][2]); ph.w = f2bf(s[n][3]);
          *(ushort4*)(Pw + qrow * 128 + ((n * 32 + lg * 8) ^ sw)) = ph;
        }
      }
      // ---- y += P @ V ----
#pragma unroll
      for (int kc = 0; kc < 2; ++kc) {
        bf16x8 pa, vtf[4];
        {
          int qrow = lr;
          pa = *(const bf16x8*)(Pw + qrow * 128 +
                                ((kc * 64 + lg * 16) ^ ((qrow & 7) << 4)));
        }
#pragma unroll
        for (int n = 0; n < 4; ++n) {
          int row = n * 16 + lr;
          vtf[n] = *(const bf16x8*)(Vc + row * 128 +
                                    ((kc * 64 + lg * 16) ^ ((row & 7) << 4)));
        }
#pragma unroll
        for (int n = 0; n < 4; ++n)
          yacc[n] = __builtin_amdgcn_mfma_f32_16x16x32_bf16(pa, vtf[n],
                                                            yacc[n], 0, 0, 0);
      }
    }
    __syncthreads();
  }

  // epilogue: reduce per-lane partial S across lane^16 / lane^32, normalize
  {
    float Sv = S;
    Sv += __shfl_xor(Sv, 16, 64);
    Sv += __shfl_xor(Sv, 32, 64);
    float inv = 1.f / Sv;
#pragma unroll
    for (int i = 0; i < 4; ++i) {
      float ivq = __shfl(inv, lg * 4 + i, 64);
#pragma unroll
      for (int n = 0; n < 4; ++n) {
        int row = b * 2048 + qbw + lg * 4 + i;
        int col = h * 64 + n * 16 + lr;
        out[(size_t)row * 1024 + col] = f2bf(yacc[n][i] * ivq);
      }
    }
  }
}

// ---------------- host launcher ---------------------------------------------
extern "C" void kernel_launch(void* const* d_in, const int* in_sizes, int n_in,
                              void* d_out, int out_size, void* d_ws, size_t ws_size,
                              hipStream_t stream) {
  const float* x  = (const float*)d_in[0];
  const float* Wq = (const float*)d_in[1];
  const float* bq = (const float*)d_in[2];
  const float* Wk = (const float*)d_in[3];
  const float* bk = (const float*)d_in[4];
  const float* Wv = (const float*)d_in[5];
  const float* bv = (const float*)d_in[6];
  const float* Wo = (const float*)d_in[7];
  const float* bo = (const float*)d_in[8];
  const float* W1 = (const float*)d_in[9];
  const float* b1 = (const float*)d_in[10];
  const float* W2 = (const float*)d_in[11];
  const float* b2 = (const float*)d_in[12];
  float* out = (float*)d_out;

  char* ws = (char*)d_ws;
  const size_t MB = 1u << 20;
  u16*   xb    = (u16*)(ws + 0);         // 8 MB  [4096,1024]  (reused as vtg later)
  u16*   wtqkv = (u16*)(ws + 8 * MB);    // 6 MB  [3072,1024]
  u16*   wto   = (u16*)(ws + 14 * MB);   // 2 MB  [1024,1024]
  u16*   wt1   = (u16*)(ws + 16 * MB);   // 8 MB  [4096,1024]
  u16*   wt2   = (u16*)(ws + 24 * MB);   // 8 MB  [1024,4096]
  float* bqkv  = (float*)(ws + 32 * MB); // 12 KB [3072]
  u16*   qkv   = (u16*)(ws + 33 * MB);   // 24 MB [4096,3072]
  u16*   attn  = (u16*)(ws + 57 * MB);   // 8 MB  [4096,1024]
  float* x2f   = (float*)(ws + 65 * MB); // 16 MB [4096,1024]
  u16*   x2b   = (u16*)(ws + 81 * MB);   // 8 MB  [4096,1024]
  u16*   hbuf  = (u16*)(ws + 89 * MB);   // 32 MB [4096,4096]
  u16*   vtg   = xb;                     // reuse: xb dead after QKV GEMM

  cvt_f32_bf16<<<2048, 256, 0, stream>>>(x, xb);
  // four 1024x1024 weight transposes in one launch
  transpose_cvt4<<<dim3(32, 32, 4), 256, 0, stream>>>(
      Wq, Wk, Wv, Wo, wtqkv, wtqkv + 1024 * 1024, wtqkv + 2 * 1024 * 1024, wto);
  // W1 + W2 transposes in one launch
  transpose_cvt_mlp<<<dim3(128, 32, 2), 256, 0, stream>>>(W1, wt1, W2, wt2);
  concat_bias<<<12, 256, 0, stream>>>(bq, bk, bv, bqkv);

  // QKV projection (fused, N=3072) — 256^2 deep-pipelined kernel (swizzled)
  gemm256_kernel<0><<<dim3(12, 16), 512, 0, stream>>>(
      xb, wtqkv, bqkv, qkv, 4096, 3072, 1024);
  // V^T for attention PV
  transpose_v<<<dim3(64, 2, 32), 256, 0, stream>>>(qkv, vtg);
  // causal attention — QBLK=128, 8 waves, 512 blocks, 48KB LDS
  attn_kernel<<<dim3(16, 32), 512, 0, stream>>>(qkv, vtg, attn);
  // O projection + residual (f32 and bf16 copies) — dbuf 128x64
  gemm_nk64_kernel<2><<<dim3(16, 32), 256, 0, stream>>>(
      attn, wto, bo, x, x2b, x2f, 4096, 1024, 1024);
  // MLP up + SiLU — 256^2 deep-pipelined kernel (swizzled)
  gemm256_kernel<1><<<dim3(16, 16), 512, 0, stream>>>(
      x2b, wt1, b1, hbuf, 4096, 4096, 1024);
  // MLP down + residual -> final f32 output — dbuf 128x64 (proven)
  gemm_nk64_kernel<3><<<dim3(16, 32), 256, 0, stream>>>(
      hbuf, wt2, b2, x2f, nullptr, out, 4096, 1024, 4096);
}

// Round 21
// 218.689 us; speedup vs baseline: 1.1432x; 1.0104x over previous
//
#include <hip/hip_runtime.h>
#include <hip/hip_bf16.h>
#include <stdint.h>

using u16 = unsigned short;
typedef __bf16 bf16x8 __attribute__((ext_vector_type(8)));
typedef float f32x4 __attribute__((ext_vector_type(4)));
typedef u16 u16x8 __attribute__((ext_vector_type(8)));

__device__ __forceinline__ float bf2f(u16 u) {
  union { unsigned int i; float f; } v; v.i = ((unsigned int)u) << 16; return v.f;
}
__device__ __forceinline__ u16 f2bf(float f) {
  __bf16 h = (__bf16)f;
  return __builtin_bit_cast(u16, h);
}
__device__ __forceinline__ float fexp2(float x) {
  return __builtin_amdgcn_exp2f(x);   // v_exp_f32: natively 2^x
}

__device__ __forceinline__ void gload_lds16(const void* g, void* l) {
  __builtin_amdgcn_global_load_lds(
      (__attribute__((address_space(1))) const void*)g,
      (__attribute__((address_space(3))) void*)l, 16, 0, 0);
}

// ---------------- elementwise convert f32 -> bf16 (8 elems/thread) ----------
__global__ void cvt_f32_bf16(const float* __restrict__ in, u16* __restrict__ out) {
  int i = (blockIdx.x * 256 + threadIdx.x) * 8;
  float4 a = *(const float4*)(in + i);
  float4 b = *(const float4*)(in + i + 4);
  u16x8 o;
  o[0] = f2bf(a.x); o[1] = f2bf(a.y); o[2] = f2bf(a.z); o[3] = f2bf(a.w);
  o[4] = f2bf(b.x); o[5] = f2bf(b.y); o[6] = f2bf(b.z); o[7] = f2bf(b.w);
  *(u16x8*)(out + i) = o;
}

// ------- batched transpose-convert of four 1024x1024 weights (one launch) ----
__global__ void transpose_cvt4(const float* __restrict__ Wa, const float* __restrict__ Wb,
                               const float* __restrict__ Wc, const float* __restrict__ Wd,
                               u16* __restrict__ Da, u16* __restrict__ Db,
                               u16* __restrict__ Dc, u16* __restrict__ Dd) {
  __shared__ float t[32][33];
  const int z = blockIdx.z;
  const float* W = (z == 0) ? Wa : (z == 1) ? Wb : (z == 2) ? Wc : Wd;
  u16* D = (z == 0) ? Da : (z == 1) ? Db : (z == 2) ? Dc : Dd;
  const int tx = threadIdx.x & 31, ty = threadIdx.x >> 5;  // 32x8
  const int n0 = blockIdx.x * 32, k0 = blockIdx.y * 32;
#pragma unroll
  for (int i = 0; i < 32; i += 8)
    t[ty + i][tx] = W[(size_t)(k0 + ty + i) * 1024 + n0 + tx];
  __syncthreads();
#pragma unroll
  for (int i = 0; i < 32; i += 8)
    D[(size_t)(n0 + ty + i) * 1024 + k0 + tx] = f2bf(t[tx][ty + i]);
}

// ------- combined transpose-convert of W1 [1024,4096] and W2 [4096,1024] -----
__global__ void transpose_cvt_mlp(const float* __restrict__ W1, u16* __restrict__ D1,
                                  const float* __restrict__ W2, u16* __restrict__ D2) {
  __shared__ float t[32][33];
  const int z = blockIdx.z;
  const float* W = z ? W2 : W1;
  u16* D = z ? D2 : D1;
  const int K = z ? 4096 : 1024, N = z ? 1024 : 4096;
  const int tx = threadIdx.x & 31, ty = threadIdx.x >> 5;  // 32x8
  const int n0 = (z ? blockIdx.y : blockIdx.x) * 32;
  const int k0 = (z ? blockIdx.x : blockIdx.y) * 32;
#pragma unroll
  for (int i = 0; i < 32; i += 8)
    t[ty + i][tx] = W[(size_t)(k0 + ty + i) * N + n0 + tx];
  __syncthreads();
#pragma unroll
  for (int i = 0; i < 32; i += 8)
    D[(size_t)(n0 + ty + i) * K + k0 + tx] = f2bf(t[tx][ty + i]);
}

// ---------------- transpose V columns of qkv -> vt[bh*64+d][2048] -----------
__global__ void transpose_v(const u16* __restrict__ qkv, u16* __restrict__ vt) {
  __shared__ u16 tile[32][34];
  const int tx = threadIdx.x & 31, ty = threadIdx.x >> 5;  // 32x8
  const int kv0 = blockIdx.x * 32, d0 = blockIdx.y * 32;
  const int bh = blockIdx.z, b = bh >> 4, h = bh & 15;
#pragma unroll
  for (int i = 0; i < 32; i += 8)
    tile[ty + i][tx] = qkv[(size_t)(b * 2048 + kv0 + ty + i) * 3072 + 2048 + h * 64 + d0 + tx];
  __syncthreads();
#pragma unroll
  for (int i = 0; i < 32; i += 8)
    vt[((size_t)bh * 64 + d0 + ty + i) * 2048 + kv0 + tx] = tile[tx][ty + i];
}

// ---------------- concat 3 biases into [3072] --------------------------------
__global__ void concat_bias(const float* __restrict__ bq, const float* __restrict__ bk,
                            const float* __restrict__ bv, float* __restrict__ o) {
  int i = blockIdx.x * 256 + threadIdx.x;
  o[i] = (i < 1024) ? bq[i] : (i < 2048 ? bk[i - 1024] : bv[i - 2048]);
}

// ============ 256x256-tile 8-wave deep-pipelined GEMM (BK=32, ring-4) ========
// LDS 16B-slots XOR-swizzled (slot^((row>>1)&3), both-sides rule).
// C = A[M,K] @ Bt[N,K]^T + bias.  EPI 0: -> bf16   EPI 1: silu -> bf16
template <int EPI>
__global__ __launch_bounds__(512, 2) void gemm256_kernel(
    const u16* __restrict__ A, const u16* __restrict__ Bt,
    const float* __restrict__ bias, u16* __restrict__ outb,
    int M, int N, int K) {
  __shared__ u16 As[4][8192];   // 4 ring slots of [256 rows][32 k] bf16
  __shared__ u16 Bs[4][8192];
  const int t = threadIdx.x;
  const int w = t >> 6, lane = t & 63, lr = lane & 15, lg = lane >> 4;
  const int wm = w >> 2, wn = w & 3;            // 2 x 4 wave grid
  const int gx = gridDim.x;
  const int nwg = gx * gridDim.y;
  const int p = blockIdx.y * gx + blockIdx.x;
  const int L = (p & 7) * (nwg >> 3) + (p >> 3);  // XCD-contiguous swizzle
  const int m0 = (L / gx) * 256, n0 = (L % gx) * 256;

  f32x4 acc[8][4] = {};
  bf16x8 bfr[4];                // B frags held across the two M-sub phases
  const int NKT = K >> 5;

  auto stageA = [&](int kt) {
#pragma unroll
    for (int l = 0; l < 2; ++l) {
      int slot = l * 512 + t;
      int row = slot >> 2, cs = slot & 3;
      int ss = cs ^ ((row >> 1) & 3);           // pre-swizzled source slot
      gload_lds16(&A[(size_t)(m0 + row) * K + kt * 32 + ss * 8], &As[kt & 3][slot * 8]);
    }
  };
  auto stageB = [&](int kt) {
#pragma unroll
    for (int l = 0; l < 2; ++l) {
      int slot = l * 512 + t;
      int row = slot >> 2, cs = slot & 3;
      int ss = cs ^ ((row >> 1) & 3);
      gload_lds16(&Bt[(size_t)(n0 + row) * K + kt * 32 + ss * 8], &Bs[kt & 3][slot * 8]);
    }
  };

  // prologue: stage subtiles 0,1,2; wait until subtile 0 landed
  stageA(0); stageB(0); stageA(1); stageB(1); stageA(2); stageB(2);
  asm volatile("s_waitcnt vmcnt(8)" ::: "memory");
  __builtin_amdgcn_s_barrier();

// one phase: 4(+4) ds_read_b128 (swizzled) + stage + bar + lgkm0 + 16 MFMA
#define PHASE(Q, STAGE)                                                          \
  {                                                                              \
    const u16* Ab = &As[kt & 3][0];                                              \
    bf16x8 af[4];                                                                \
    _Pragma("unroll") for (int m = 0; m < 4; ++m) {                              \
      int row = wm * 128 + ((Q) * 4 + m) * 16 + lr;                              \
      int sl = lg ^ ((row >> 1) & 3);                                            \
      af[m] = *(const bf16x8*)&Ab[row * 32 + sl * 8];                            \
    }                                                                            \
    if ((Q) == 0) {                                                              \
      const u16* Bb = &Bs[kt & 3][0];                                            \
      _Pragma("unroll") for (int n = 0; n < 4; ++n) {                            \
        int row = wn * 64 + n * 16 + lr;                                         \
        int sl = lg ^ ((row >> 1) & 3);                                          \
        bfr[n] = *(const bf16x8*)&Bb[row * 32 + sl * 8];                         \
      }                                                                          \
    }                                                                            \
    STAGE;                                                                       \
    __builtin_amdgcn_s_barrier();                                                \
    asm volatile("s_waitcnt lgkmcnt(0)" ::: "memory");                           \
    __builtin_amdgcn_sched_barrier(0);                                           \
    __builtin_amdgcn_s_setprio(1);                                               \
    _Pragma("unroll") for (int m = 0; m < 4; ++m)                                \
        _Pragma("unroll") for (int n = 0; n < 4; ++n)                            \
            acc[(Q) * 4 + m][n] = __builtin_amdgcn_mfma_f32_16x16x32_bf16(       \
                af[m], bfr[n], acc[(Q) * 4 + m][n], 0, 0, 0);                    \
    __builtin_amdgcn_s_setprio(0);                                               \
  }

  int kt = 0;
  for (; kt < NKT - 3; ++kt) {
    PHASE(0, stageA(kt + 3));
    __builtin_amdgcn_s_barrier();
    PHASE(1, stageB(kt + 3));
    // counted wait: subtiles kt+2, kt+3 stay in flight; kt+1 landed
    asm volatile("s_waitcnt vmcnt(8)" ::: "memory");
    __builtin_amdgcn_s_barrier();
  }
  // tail: everything staged; drain once, then pure compute
  asm volatile("s_waitcnt vmcnt(0)" ::: "memory");
  __builtin_amdgcn_s_barrier();
  for (; kt < NKT; ++kt) {
    PHASE(0, (void)0);
    __builtin_amdgcn_s_barrier();
    PHASE(1, (void)0);
    __builtin_amdgcn_s_barrier();
  }
#undef PHASE

  // epilogue
#pragma unroll
  for (int mf = 0; mf < 8; ++mf)
#pragma unroll
    for (int nf = 0; nf < 4; ++nf)
#pragma unroll
      for (int i = 0; i < 4; ++i) {
        int gr = m0 + wm * 128 + mf * 16 + lg * 4 + i;
        int gc = n0 + wn * 64 + nf * 16 + lr;
        float v = acc[mf][nf][i] + bias[gc];
        if constexpr (EPI == 1) v = v / (1.f + __expf(-v));  // silu
        outb[(size_t)gr * N + gc] = f2bf(v);
      }
}

// ---------------- GEMM 128x64 tile, double-buffered (N=1024 shapes) ----------
// FINAL structure (5 variants regressed). EPI 2: + f32 resid -> bf16 only.
// EPI 3: + bf16 resid -> f32 out (final output).
template <int EPI>
__global__ __launch_bounds__(256) void gemm_nk64_kernel(
    const u16* __restrict__ A, const u16* __restrict__ Bt,
    const float* __restrict__ bias, const float* __restrict__ residf,
    const u16* __restrict__ residb,
    u16* __restrict__ outb, float* __restrict__ outf, int M, int N, int K) {
  __shared__ u16 As[2][128 * 64];
  __shared__ u16 Bs[2][64 * 64];
  const int t = threadIdx.x;
  const int w = t >> 6, lane = t & 63, lr = lane & 15, lg = lane >> 4;
  const int wm = w >> 1, wn = w & 1;          // 2(M) x 2(N) waves
  const int gx = gridDim.x;                    // N/64
  const int nwg = gx * gridDim.y;
  const int p = blockIdx.y * gx + blockIdx.x;
  const int L = (p & 7) * (nwg >> 3) + (p >> 3);  // XCD-contiguous swizzle
  const int m0 = (L / gx) * 128, n0 = (L % gx) * 64;

  f32x4 acc[4][2] = {};
  const int nt = K >> 6;

  auto stage = [&](int kt, int buf) {
#pragma unroll
    for (int it = 0; it < 4; ++it) {
      int ofs = (it * 256 + t) * 8;
      int row = ofs >> 6, slot = (ofs >> 3) & 7, ss = slot ^ (row & 7);
      gload_lds16(&A[(size_t)(m0 + row) * K + kt * 64 + ss * 8], &As[buf][ofs]);
    }
#pragma unroll
    for (int it = 0; it < 2; ++it) {
      int ofs = (it * 256 + t) * 8;
      int row = ofs >> 6, slot = (ofs >> 3) & 7, ss = slot ^ (row & 7);
      gload_lds16(&Bt[(size_t)(n0 + row) * K + kt * 64 + ss * 8], &Bs[buf][ofs]);
    }
  };

  stage(0, 0);
  __syncthreads();

  for (int kt = 0; kt < nt; ++kt) {
    const int cur = kt & 1;
    if (kt + 1 < nt) stage(kt + 1, cur ^ 1);   // issue next-tile loads early
#pragma unroll
    for (int kk = 0; kk < 64; kk += 32) {
      const int kcol = kk + lg * 8;
      bf16x8 af[4], bfr[2];
#pragma unroll
      for (int m = 0; m < 4; ++m) {
        int row = wm * 64 + m * 16 + lr;
        int ss = (kcol >> 3) ^ (row & 7);
        af[m] = *(const bf16x8*)&As[cur][row * 64 + ss * 8];
      }
#pragma unroll
      for (int n = 0; n < 2; ++n) {
        int row = wn * 32 + n * 16 + lr;
        int ss = (kcol >> 3) ^ (row & 7);
        bfr[n] = *(const bf16x8*)&Bs[cur][row * 64 + ss * 8];
      }
#pragma unroll
      for (int m = 0; m < 4; ++m)
#pragma unroll
        for (int n = 0; n < 2; ++n)
          acc[m][n] = __builtin_amdgcn_mfma_f32_16x16x32_bf16(af[m], bfr[n],
                                                              acc[m][n], 0, 0, 0);
    }
    __syncthreads();   // drains vmcnt (next tile landed) + lgkm, barrier
  }

  const int r0 = m0 + wm * 64, c0 = n0 + wn * 32;
#pragma unroll
  for (int m = 0; m < 4; ++m)
#pragma unroll
    for (int n = 0; n < 2; ++n)
#pragma unroll
      for (int i = 0; i < 4; ++i) {
        int gr = r0 + m * 16 + lg * 4 + i;
        int gc = c0 + n * 16 + lr;
        float v = acc[m][n][i] + bias[gc];
        if constexpr (EPI == 2) {
          v += residf[(size_t)gr * N + gc];
          outb[(size_t)gr * N + gc] = f2bf(v);
        }
        if constexpr (EPI == 3) {
          v += bf2f(residb[(size_t)gr * N + gc]);
          outf[(size_t)gr * N + gc] = v;
        }
      }
}

// ---------------- causal flash attention: QBLK=128, 8 waves, no-max exp2 -----
__global__ __launch_bounds__(512) void attn_kernel(const u16* __restrict__ qkv,
                                                   const u16* __restrict__ vtg,
                                                   u16* __restrict__ out) {
  __shared__ u16 smem[24576];      // 48 KB
  const int t = threadIdx.x, w = t >> 6, lane = t & 63, lr = lane & 15, lg = lane >> 4;
  const int p = blockIdx.y * 16 + blockIdx.x;
  const int L = (p & 7) * 64 + (p >> 3);          // XCD-contiguous swizzle
  const int qt = 15 - (L & 15), bh = L >> 4, b = bh >> 4, h = bh & 15;
  const int qbw = qt * 128 + w * 16;              // this wave's first q row
  const int jmax_blk = 2 * qt + 1;
  const int jmax_w = 2 * qt + (w >> 2);           // waves 4-7 need the last tile

  // Q pre-scaled by (1/8)*log2(e): QK^T result is directly the exp2 argument
  const float QS = 0.18033688011f;
  bf16x8 qf[2];
#pragma unroll
  for (int kc = 0; kc < 2; ++kc) {
    const u16x8 v = *(const u16x8*)&qkv[(size_t)(b * 2048 + qbw + lr) * 3072 +
                                        h * 64 + kc * 32 + lg * 8];
    bf16x8 q;
#pragma unroll
    for (int jj = 0; jj < 8; ++jj) q[jj] = (__bf16)(bf2f(v[jj]) * QS);
    qf[kc] = q;
  }

  f32x4 yacc[4] = {};
  float S = 0.f;   // per-lane partial denominator

  auto stage = [&](int j, int buf) {
    u16* Kb = smem + buf * 4096;
    u16* Vb = smem + 8192 + buf * 4096;
    int ofs = t * 8;                              // 512 threads x 8 elems = tile
    int row = ofs >> 6, slot = (ofs >> 3) & 7, ss = slot ^ (row & 7);
    gload_lds16(&qkv[(size_t)(b * 2048 + j * 64 + row) * 3072 + 1024 + h * 64 + ss * 8],
                &Kb[ofs]);
    gload_lds16(&vtg[((size_t)bh * 64 + row) * 2048 + j * 64 + ss * 8],
                &Vb[ofs]);
  };

  stage(0, 0);
  __syncthreads();

  for (int j = 0; j <= jmax_blk; ++j) {
    const int cur = j & 1;
    if (j < jmax_blk) stage(j + 1, cur ^ 1);

    if (j <= jmax_w) {
      const char* Kc = (const char*)(smem + cur * 4096);
      const char* Vc = (const char*)(smem + 8192 + cur * 4096);
      char* Pw = (char*)(smem + 16384 + w * 1024);

      // ---- S^T = K @ Q^T : lane holds S[q=lr][k=n*16+lg*4+i] ----
      bf16x8 kf[2][4];
#pragma unroll
      for (int kc = 0; kc < 2; ++kc)
#pragma unroll
        for (int n = 0; n < 4; ++n) {
          int row = n * 16 + lr;
          kf[kc][n] = *(const bf16x8*)(Kc + row * 128 +
                                       ((kc * 64 + lg * 16) ^ ((row & 7) << 4)));
        }
      f32x4 s[4] = {};
#pragma unroll
      for (int n = 0; n < 4; ++n)
#pragma unroll
        for (int kc = 0; kc < 2; ++kc)
          s[n] = __builtin_amdgcn_mfma_f32_16x16x32_bf16(kf[kc][n], qf[kc],
                                                         s[n], 0, 0, 0);
      // causal mask (tiles overlapping the diagonal for this wave)
      if (j * 64 + 63 > qbw) {
#pragma unroll
        for (int n = 0; n < 4; ++n)
#pragma unroll
          for (int i = 0; i < 4; ++i) {
            int kabs = j * 64 + n * 16 + lg * 4 + i;
            int qabs = qbw + lr;
            if (kabs > qabs) s[n][i] = -1e30f;   // exp2 -> 0
          }
      }
      // ---- unnormalized softmax: p = 2^s, per-lane partial sums ----
      {
        float rs = 0.f;
#pragma unroll
        for (int n = 0; n < 4; ++n)
#pragma unroll
          for (int i = 0; i < 4; ++i) {
            float pv = fexp2(s[n][i]);
            s[n][i] = pv;
            rs += pv;
          }
        S += rs;
        const int qrow = lr, sw = (qrow & 7) << 4;
#pragma unroll
        for (int n = 0; n < 4; ++n) {
          ushort4 ph;
          ph.x = f2bf(s[n][0]); ph.y = f2bf(s[n][1]);
          ph.z = f2bf(s[n][2]); ph.w = f2bf(s[n][3]);
          *(ushort4*)(Pw + qrow * 128 + ((n * 32 + lg * 8) ^ sw)) = ph;
        }
      }
      // ---- y += P @ V ----
#pragma unroll
      for (int kc = 0; kc < 2; ++kc) {
        bf16x8 pa, vtf[4];
        {
          int qrow = lr;
          pa = *(const bf16x8*)(Pw + qrow * 128 +
                                ((kc * 64 + lg * 16) ^ ((qrow & 7) << 4)));
        }
#pragma unroll
        for (int n = 0; n < 4; ++n) {
          int row = n * 16 + lr;
          vtf[n] = *(const bf16x8*)(Vc + row * 128 +
                                    ((kc * 64 + lg * 16) ^ ((row & 7) << 4)));
        }
#pragma unroll
        for (int n = 0; n < 4; ++n)
          yacc[n] = __builtin_amdgcn_mfma_f32_16x16x32_bf16(pa, vtf[n],
                                                            yacc[n], 0, 0, 0);
      }
    }
    __syncthreads();
  }

  // epilogue: reduce per-lane partial S across lane^16 / lane^32, normalize
  {
    float Sv = S;
    Sv += __shfl_xor(Sv, 16, 64);
    Sv += __shfl_xor(Sv, 32, 64);
    float inv = 1.f / Sv;
#pragma unroll
    for (int i = 0; i < 4; ++i) {
      float ivq = __shfl(inv, lg * 4 + i, 64);
#pragma unroll
      for (int n = 0; n < 4; ++n) {
        int row = b * 2048 + qbw + lg * 4 + i;
        int col = h * 64 + n * 16 + lr;
        out[(size_t)row * 1024 + col] = f2bf(yacc[n][i] * ivq);
      }
    }
  }
}

// ---------------- host launcher ---------------------------------------------
extern "C" void kernel_launch(void* const* d_in, const int* in_sizes, int n_in,
                              void* d_out, int out_size, void* d_ws, size_t ws_size,
                              hipStream_t stream) {
  const float* x  = (const float*)d_in[0];
  const float* Wq = (const float*)d_in[1];
  const float* bq = (const float*)d_in[2];
  const float* Wk = (const float*)d_in[3];
  const float* bk = (const float*)d_in[4];
  const float* Wv = (const float*)d_in[5];
  const float* bv = (const float*)d_in[6];
  const float* Wo = (const float*)d_in[7];
  const float* bo = (const float*)d_in[8];
  const float* W1 = (const float*)d_in[9];
  const float* b1 = (const float*)d_in[10];
  const float* W2 = (const float*)d_in[11];
  const float* b2 = (const float*)d_in[12];
  float* out = (float*)d_out;

  char* ws = (char*)d_ws;
  const size_t MB = 1u << 20;
  u16*   xb    = (u16*)(ws + 0);         // 8 MB  [4096,1024]  (reused as vtg later)
  u16*   wtqkv = (u16*)(ws + 8 * MB);    // 6 MB  [3072,1024]
  u16*   wto   = (u16*)(ws + 14 * MB);   // 2 MB  [1024,1024]
  u16*   wt1   = (u16*)(ws + 16 * MB);   // 8 MB  [4096,1024]
  u16*   wt2   = (u16*)(ws + 24 * MB);   // 8 MB  [1024,4096]
  float* bqkv  = (float*)(ws + 32 * MB); // 12 KB [3072]
  u16*   qkv   = (u16*)(ws + 33 * MB);   // 24 MB [4096,3072]
  u16*   attn  = (u16*)(ws + 57 * MB);   // 8 MB  [4096,1024]
  u16*   x2b   = (u16*)(ws + 81 * MB);   // 8 MB  [4096,1024]
  u16*   hbuf  = (u16*)(ws + 89 * MB);   // 32 MB [4096,4096]
  u16*   vtg   = xb;                     // reuse: xb dead after QKV GEMM

  cvt_f32_bf16<<<2048, 256, 0, stream>>>(x, xb);
  // four 1024x1024 weight transposes in one launch
  transpose_cvt4<<<dim3(32, 32, 4), 256, 0, stream>>>(
      Wq, Wk, Wv, Wo, wtqkv, wtqkv + 1024 * 1024, wtqkv + 2 * 1024 * 1024, wto);
  // W1 + W2 transposes in one launch
  transpose_cvt_mlp<<<dim3(128, 32, 2), 256, 0, stream>>>(W1, wt1, W2, wt2);
  concat_bias<<<12, 256, 0, stream>>>(bq, bk, bv, bqkv);

  // QKV projection (fused, N=3072) — 256^2 deep-pipelined kernel (swizzled)
  gemm256_kernel<0><<<dim3(12, 16), 512, 0, stream>>>(
      xb, wtqkv, bqkv, qkv, 4096, 3072, 1024);
  // V^T for attention PV
  transpose_v<<<dim3(64, 2, 32), 256, 0, stream>>>(qkv, vtg);
  // causal attention — QBLK=128, 8 waves, 512 blocks, 48KB LDS
  attn_kernel<<<dim3(16, 32), 512, 0, stream>>>(qkv, vtg, attn);
  // O projection + residual -> bf16 x2 only (residual carried in bf16)
  gemm_nk64_kernel<2><<<dim3(16, 32), 256, 0, stream>>>(
      attn, wto, bo, x, nullptr, x2b, nullptr, 4096, 1024, 1024);
  // MLP up + SiLU — 256^2 deep-pipelined kernel (swizzled)
  gemm256_kernel<1><<<dim3(16, 16), 512, 0, stream>>>(
      x2b, wt1, b1, hbuf, 4096, 4096, 1024);
  // MLP down + bf16 residual -> final f32 output
  gemm_nk64_kernel<3><<<dim3(16, 32), 256, 0, stream>>>(
      hbuf, wt2, b2, nullptr, x2b, nullptr, out, 4096, 1024, 4096);
}